// Round 11
// baseline (333.787 us; speedup 1.0000x reference)
//
#include <hip/hip_runtime.h>
#include <hip/hip_bf16.h>

// Problem constants
#define BB 4
#define TT 2048
#define DD 1024
#define HH 16
#define SS 64
#define CH 64
#define NC (TT/CH)        // 32
#define M_ROWS (BB*TT)    // 8192
#define COL 68            // LDS row stride (words): 272B, 16B-aligned rows, <=2-way b128 reads

typedef __hip_bfloat16 bf16;
using int4v  = __attribute__((ext_vector_type(4))) int;
using short8 = __attribute__((ext_vector_type(8))) short;
using f32x4  = __attribute__((ext_vector_type(4))) float;

#if defined(__has_builtin)
#if __has_builtin(__builtin_amdgcn_global_load_lds)
#define HAVE_GLL 1
#endif
#if __has_builtin(__builtin_amdgcn_mfma_i32_16x16x64_i8)
#define HAVE_I8K64 1
#endif
#endif

#ifdef HAVE_GLL
// async global->LDS, 16 B per lane; LDS dst contiguous in lane order
static __device__ __forceinline__ void gload16(const void* g, void* l) {
  __builtin_amdgcn_global_load_lds(
      (const __attribute__((address_space(1))) void*)g,
      (__attribute__((address_space(3))) void*)l, 16, 0, 0);
}
#endif

// ---- wave-wide sum (64 lanes, deterministic butterfly) ----
static __device__ __forceinline__ float wave_sum(float v) {
  #pragma unroll
  for (int d = 1; d < 64; d <<= 1) v += __shfl_xor(v, d);
  return v;
}

// ---- block sum over 256 threads: shfl + 4-slot LDS, ONE barrier. ----
static __device__ __forceinline__ float block_sum4(float v, float* slot, int tid) {
  float w = wave_sum(v);
  if ((tid & 63) == 0) slot[tid >> 6] = w;
  __syncthreads();
  return slot[0] + slot[1] + slot[2] + slot[3];
}

static __device__ __forceinline__ int pack4(int a, int b, int c, int d) {
  return (a & 0xff) | ((b & 0xff) << 8) | ((c & 0xff) << 16) | ((d & 0xff) << 24);
}

// ---- split-bf16: pack f32 as (hi bf16 | lo bf16), reconstruction ~2^-16 rel ----
static __device__ __forceinline__ unsigned packsplit(float f) {
  unsigned b  = __float_as_uint(f);
  unsigned hb = b & 0xffff0000u;                 // truncated bf16 (bits in [31:16])
  float fl = f - __uint_as_float(hb);            // exact remainder
  unsigned lb = __float_as_uint(fl) >> 16;       // truncated bf16 of remainder
  return hb | lb;
}

static __device__ __forceinline__ void unpk8(const unsigned* q, short8& h, short8& l) {
  uint4 q0 = *(const uint4*)q;
  uint4 q1 = *(const uint4*)(q + 4);
  unsigned ar[8] = {q0.x, q0.y, q0.z, q0.w, q1.x, q1.y, q1.z, q1.w};
  #pragma unroll
  for (int e = 0; e < 8; e++) {
    h[e] = (short)(ar[e] >> 16);
    l[e] = (short)(ar[e] & 0xffffu);
  }
}

// ---- K0: decay/exponential tables.
// P1=e^{+d t}, P2=e^{-d(t+1)}, K1F=e^{-d t}, K2F=e^{-d(63-t)}, EU=e^u. ----
__global__ __launch_bounds__(64) void k_tab(const float* __restrict__ log_decay,
                                            const float* __restrict__ u,
                                            float* __restrict__ P1t,
                                            float* __restrict__ P2t,
                                            float* __restrict__ K1Ft,
                                            float* __restrict__ K2Ft,
                                            float* __restrict__ EUt) {
  int blk = blockIdx.x;              // h*64 + t
  int h = blk >> 6, t = blk & 63;
  int s = threadIdx.x;
  float d = expf(log_decay[h * SS + s]);
  size_t idx = (size_t)blk * SS + s;
  P1t[idx]  = expf(d * (float)t);
  P2t[idx]  = expf(-d * (float)(t + 1));
  K1Ft[idx] = expf(-d * (float)t);        // c == t role
  K2Ft[idx] = expf(-d * (float)(63 - t)); // decay-to-chunk-end
  if (t == 0) EUt[h * SS + s] = expf(u[h * SS + s]);
}

// ---- K1a: weight-scale partials. grid (5,64) ----
__global__ __launch_bounds__(256) void k_wscale_part(const float* __restrict__ w,
                                                     double* __restrict__ wpart) {
  __shared__ double red[256];
  int i = blockIdx.x, b = blockIdx.y, tid = threadIdx.x;
  const float* base = w + (size_t)i * DD * DD + (size_t)b * 16384;
  double s = 0.0;
  #pragma unroll
  for (int j = 0; j < 64; j++) s += (double)fabsf(base[tid + j * 256]);
  red[tid] = s; __syncthreads();
  for (int o = 128; o > 0; o >>= 1) {
    if (tid < o) red[tid] += red[tid + o];
    __syncthreads();
  }
  if (tid == 0) wpart[i * 64 + b] = red[0];
}

// ---- K1b: fold 64 partials per matrix in fixed order ----
__global__ __launch_bounds__(64) void k_wscale_fin(const double* __restrict__ wpart,
                                                   float* __restrict__ wscale) {
  int i = blockIdx.x;
  if (threadIdx.x == 0) {
    double s = 0.0;
    for (int b = 0; b < 64; b++) s += wpart[i * 64 + b];
    wscale[i] = fmaxf((float)(s * (1.0 / (DD * DD))), 1e-8f);
  }
}

// ---- K2 v2: ternary weight quant -> int8 {-1,0,1}, packed int stores ----
__global__ __launch_bounds__(256) void k_wquant(const float* __restrict__ w,
                                                const float* __restrict__ wscale,
                                                char* __restrict__ wq) {
  int idx4 = (blockIdx.x * 256 + threadIdx.x) * 4;   // < 5*1024*1024
  int i = idx4 >> 20;
  float ws = wscale[i];
  float4 w4 = *(const float4*)&w[idx4];
  float vals[4] = {w4.x, w4.y, w4.z, w4.w};
  int q[4];
  #pragma unroll
  for (int j = 0; j < 4; j++) {
    float wn = fminf(fmaxf(vals[j] / ws, -1.f), 1.f);
    q[j] = (int)rintf(wn);
  }
  *(int*)&wq[idx4] = pack4(q[0], q[1], q[2], q[3]);
}

// ---- K3 v3: FUSED token-shift + LN + act-quant, int8 out, float4 loads. ----
__global__ __launch_bounds__(256) void k_prep_quant(
    const float* __restrict__ x, const float* __restrict__ mu_r,
    const float* __restrict__ mu_k, const float* __restrict__ mu_v,
    const float* __restrict__ mu_g, const float* __restrict__ ln_g,
    const float* __restrict__ ln_b, char* __restrict__ xq,
    float* __restrict__ ascale) {
  __shared__ float slots[12 * 4];
  int m = blockIdx.x, tid = threadIdx.x;
  int t = m & (TT - 1);
  const float* xr = x + (size_t)m * DD;
  int d4 = tid * 4;
  float4 xv4 = *(const float4*)&xr[d4];
  float4 xs4 = (t > 0) ? *(const float4*)&xr[d4 - DD]
                       : (float4){0.f, 0.f, 0.f, 0.f};
  float xv[4] = {xv4.x, xv4.y, xv4.z, xv4.w};
  float xs[4] = {xs4.x, xs4.y, xs4.z, xs4.w};
  const float* mus[4] = {mu_r, mu_k, mu_v, mu_g};
  #pragma unroll 1
  for (int i = 0; i < 4; i++) {
    float4 mu4 = *(const float4*)&mus[i][d4];
    float mu[4] = {mu4.x, mu4.y, mu4.z, mu4.w};
    float inp[4];
    #pragma unroll
    for (int j = 0; j < 4; j++) inp[j] = xv[j] + (xs[j] - xv[j]) * mu[j];
    float mean = block_sum4(inp[0] + inp[1] + inp[2] + inp[3],
                            &slots[(i * 3 + 0) * 4], tid) * (1.f / DD);
    float var = 0.f;
    #pragma unroll
    for (int j = 0; j < 4; j++) { float dv = inp[j] - mean; var += dv * dv; }
    var = block_sum4(var, &slots[(i * 3 + 1) * 4], tid) * (1.f / DD);
    float rstd = 1.f / sqrtf(var + 1e-5f);
    float4 lg4 = *(const float4*)&ln_g[i * DD + d4];
    float4 lb4 = *(const float4*)&ln_b[i * DD + d4];
    float lg[4] = {lg4.x, lg4.y, lg4.z, lg4.w};
    float lb[4] = {lb4.x, lb4.y, lb4.z, lb4.w};
    float ln[4]; float aabs = 0.f;
    #pragma unroll
    for (int j = 0; j < 4; j++) {
      ln[j] = (inp[j] - mean) * rstd * lg[j] + lb[j];
      aabs += fabsf(ln[j]);
    }
    float meanabs = block_sum4(aabs, &slots[(i * 3 + 2) * 4], tid) * (1.f / DD);
    float scale = fmaxf(meanabs, 1e-8f) * 2.5f * (1.f / 127.f);
    int q[4];
    #pragma unroll
    for (int j = 0; j < 4; j++)
      q[j] = (int)rintf(fminf(fmaxf(ln[j] / scale, -127.f), 127.f));
    *(int*)&xq[((size_t)i * M_ROWS + m) * DD + d4] = pack4(q[0], q[1], q[2], q[3]);
    if (tid == 0) ascale[i * M_ROWS + m] = scale;
  }
}

// ---- K4/K9 v5: INT8 MFMA GEMM, 256x256 tile, BK=64, 8 waves (512 thr),
// counted-vmcnt deep pipeline (T3+T4): 3 LDS buffers (96 KB), tile kt+2's
// 4 staging passes issue during tile kt's 4 compute phases; tile boundary =
// s_waitcnt vmcnt(4) (never 0 in steady state) + raw s_barrier.
// T2 swizzle BOTH-sides (rule #21), within-64B-row only: LDS(row,slot) holds
// global (row, slot^((row>>1)&3)) — staging permutes the per-lane GLOBAL slot
// inside each 64B line (preserves TA merging; R9's cross-line permute did not),
// frag reads apply the same XOR -> rows spread over 8/8 16B slots (2-way, free).
// T5 setprio around MFMA cluster. Integer-exact: bit-identical output. ----
__global__ __launch_bounds__(512) void k_gemm(
    const char* __restrict__ Axq, const char* __restrict__ Wq,
    const float* __restrict__ ascale, const float* __restrict__ wscale,
    int projbase, float* __restrict__ outF) {
  __shared__ __align__(16) char As[3][256 * 64];   // 48 KB
  __shared__ __align__(16) char Bs[3][256 * 64];   // 48 KB
  int tid = threadIdx.x;
  int wvid = tid >> 6, lane = tid & 63;
  int wm = wvid >> 2, wn = wvid & 3;               // 2 x 4 wave grid
  int m0 = blockIdx.x * 256, n0 = blockIdx.y * 256;
  int z = blockIdx.z;
  int proj = projbase + z;
  const char* Ap = Axq + ((size_t)z * M_ROWS + m0) * DD;
  const char* Wp = Wq + ((size_t)proj * DD + n0) * DD;
  int4v acc[8][4];
  #pragma unroll
  for (int i = 0; i < 8; i++)
    #pragma unroll
    for (int j = 0; j < 4; j++) acc[i][j] = (int4v){0, 0, 0, 0};

  int frow = lane & 15, fslot = lane >> 4;
  // staging: pass q in 0..3 (q<2: A rows 128q.., else B rows 128(q-2)..)
  int srow_lo = tid >> 2;                           // 0..127
  int sslot0  = tid & 3;

  auto stage_pass = [&](int k0, int q, char* Ad, char* Bd) {
    int rr = ((q & 1) << 7) + srow_lo;              // row within 256-row tile
    int sl = sslot0 ^ ((rr >> 1) & 3);              // pre-swizzled global slot
    if (q < 2) {
#ifdef HAVE_GLL
      gload16(&Ap[(size_t)rr * DD + k0 + sl * 16], &Ad[(q & 1) * 8192 + tid * 16]);
#else
      *(uint4*)&Ad[(q & 1) * 8192 + tid * 16] =
          *(const uint4*)&Ap[(size_t)rr * DD + k0 + sl * 16];
#endif
    } else {
#ifdef HAVE_GLL
      gload16(&Wp[(size_t)rr * DD + k0 + sl * 16], &Bd[(q & 1) * 8192 + tid * 16]);
#else
      *(uint4*)&Bd[(q & 1) * 8192 + tid * 16] =
          *(const uint4*)&Wp[(size_t)rr * DD + k0 + sl * 16];
#endif
    }
  };

  // prologue: stage tile0 -> buf0, tile1 -> buf1 (8 issues); wait oldest 4
  #pragma unroll
  for (int q = 0; q < 4; q++) stage_pass(0, q, As[0], Bs[0]);
  #pragma unroll
  for (int q = 0; q < 4; q++) stage_pass(64, q, As[1], Bs[1]);
#ifdef HAVE_GLL
  asm volatile("s_waitcnt vmcnt(4)" ::: "memory");
  __builtin_amdgcn_s_barrier();
#else
  __syncthreads();
#endif

  for (int kt = 0; kt < 16; ++kt) {
    const char* Abuf = As[kt % 3];
    const char* Bbuf = Bs[kt % 3];
    char* Anx = As[(kt + 2) % 3];
    char* Bnx = Bs[(kt + 2) % 3];
    int k0n = (kt + 2) * 64;
    bool do_stage = (kt + 2) < 16;
    // B-frags for this tile (held across phases)
    int4v bfr[4];
    #pragma unroll
    for (int j = 0; j < 4; j++) {
      int r = 64 * wn + 16 * j + frow;
      bfr[j] = *(const int4v*)&Bbuf[r * 64 + (fslot ^ ((r >> 1) & 3)) * 16];
    }
    #pragma unroll
    for (int p = 0; p < 4; p++) {
      if (do_stage) stage_pass(k0n, p, Anx, Bnx);
      int4v af[2];
      #pragma unroll
      for (int e = 0; e < 2; e++) {
        int r = 128 * wm + 16 * (2 * p + e) + frow;
        af[e] = *(const int4v*)&Abuf[r * 64 + (fslot ^ ((r >> 1) & 3)) * 16];
      }
      __builtin_amdgcn_s_setprio(1);
#ifdef HAVE_I8K64
      #pragma unroll
      for (int e = 0; e < 2; e++)
        #pragma unroll
        for (int j = 0; j < 4; j++)
          acc[2 * p + e][j] =
              __builtin_amdgcn_mfma_i32_16x16x64_i8(af[e], bfr[j], acc[2 * p + e][j], 0, 0, 0);
#else
      // K=32 fallback: split each 16B frag into two 8B halves via regs
      #pragma unroll
      for (int e = 0; e < 2; e++)
        #pragma unroll
        for (int j = 0; j < 4; j++)
          #pragma unroll
          for (int hh2 = 0; hh2 < 2; hh2++) {
            long a8, b8;
            memcpy(&a8, ((const char*)&af[e]) + hh2 * 8, 8);
            memcpy(&b8, ((const char*)&bfr[j]) + hh2 * 8, 8);
            acc[2 * p + e][j] =
                __builtin_amdgcn_mfma_i32_16x16x32_i8(a8, b8, acc[2 * p + e][j], 0, 0, 0);
          }
#endif
      __builtin_amdgcn_s_setprio(0);
    }
    if (kt < 15) {
#ifdef HAVE_GLL
      if (kt + 2 < 16) asm volatile("s_waitcnt vmcnt(4)" ::: "memory");
      else             asm volatile("s_waitcnt vmcnt(0)" ::: "memory");
      __builtin_amdgcn_s_barrier();
#else
      __syncthreads();
#endif
    }
  }

  const float* asc = ascale + (size_t)z * M_ROWS + m0;
  float wsc = wscale[proj];
  int col = lane & 15, rg = lane >> 4;
  #pragma unroll
  for (int i = 0; i < 8; i++) {
    #pragma unroll
    for (int r = 0; r < 4; r++) {
      int mm = 128 * wm + 16 * i + rg * 4 + r;
      float s = asc[mm] * wsc;
      #pragma unroll
      for (int j = 0; j < 4; j++) {
        int nn = 64 * wn + 16 * j + col;
        outF[((size_t)z * M_ROWS + m0 + mm) * DD + (n0 + nn)] = (float)acc[i][j][r] * s;
      }
    }
  }
}

// ---- K5 v2: MFMA injection (verified R10). inj[s][o] = sum_t K2[t,s]*v[t,o]. ----
__global__ __launch_bounds__(256) void k_inj_mm(const float* __restrict__ rkvg,
                                                const float* __restrict__ K2Ft,
                                                float* __restrict__ states) {
#if defined(__HIP_DEVICE_COMPILE__)
  __shared__ __align__(16) unsigned k2t[64 * COL];   // K2^T[s][t], hi|lo
  __shared__ __align__(16) unsigned vtsh[64 * COL];  // V^T[o][t], hi|lo
  int blk = blockIdx.x, tid = threadIdx.x;
  int n = blk & (NC - 1), h = (blk >> 5) & (HH - 1), b = blk >> 9;
  size_t rowbase = ((size_t)b * TT + n * CH) * DD + h * SS;
  const float* Kp = rkvg + (size_t)1 * M_ROWS * DD + rowbase;
  const float* Vp = rkvg + (size_t)2 * M_ROWS * DD + rowbase;
  const float* K2h = K2Ft + (size_t)h * SS * SS;

  int s_me = tid & 63, c0 = tid >> 6;
  #pragma unroll 4
  for (int j = 0; j < 16; j++) {
    int c = c0 + 4 * j;                              // t index
    float kv = Kp[(size_t)c * DD + s_me];
    float vv = Vp[(size_t)c * DD + s_me];
    k2t[s_me * COL + c] = packsplit(kv * K2h[(size_t)c * SS + s_me]);
    vtsh[s_me * COL + c] = packsplit(vv);
  }
  __syncthreads();

  int wid = tid >> 6, lane = tid & 63;
  int s_row = wid * 16 + (lane & 15);                // A-frag row (s)
  int koff = (lane >> 4) * 8;                        // t offset within K=32
  short8 ah[2], al[2];
  #pragma unroll
  for (int kh = 0; kh < 2; kh++)
    unpk8(&k2t[s_row * COL + kh * 32 + koff], ah[kh], al[kh]);

  float* st = states + (size_t)blk * SS * SS;
  #pragma unroll 1
  for (int ot = 0; ot < 4; ot++) {
    int o_row = ot * 16 + (lane & 15);
    f32x4 acc = {0.f, 0.f, 0.f, 0.f};
    #pragma unroll
    for (int kh = 0; kh < 2; kh++) {
      short8 vh, vl;
      unpk8(&vtsh[o_row * COL + kh * 32 + koff], vh, vl);
      acc = __builtin_amdgcn_mfma_f32_16x16x32_bf16(ah[kh], vh, acc, 0, 0, 0);
      acc = __builtin_amdgcn_mfma_f32_16x16x32_bf16(ah[kh], vl, acc, 0, 0, 0);
      acc = __builtin_amdgcn_mfma_f32_16x16x32_bf16(al[kh], vh, acc, 0, 0, 0);
    }
    #pragma unroll
    for (int rr = 0; rr < 4; rr++) {
      int s = wid * 16 + (lane >> 4) * 4 + rr;       // C row (m89)
      int o = ot * 16 + (lane & 15);                 // C col
      st[(size_t)s * SS + o] = acc[rr];
    }
  }
#endif  // __HIP_DEVICE_COMPILE__
}

// ---- K6 v2: PARALLEL scan, loads hoisted ahead of the serial chain ----
__global__ __launch_bounds__(256) void k_scan(const float* __restrict__ log_decay,
                                              float* __restrict__ states) {
  int blk = blockIdx.x;
  int bh = blk >> 4, sb = blk & 15;
  int h = bh & (HH - 1);
  int tid = threadIdx.x;
  int js = tid >> 6, o = tid & 63;
  int s = sb * 4 + js;
  float wC = expf(-64.f * expf(log_decay[h * SS + s]));
  float* base = states + (size_t)bh * NC * SS * SS + (size_t)s * SS + o;
  float inj[NC];
  #pragma unroll
  for (int n = 0; n < NC; n++) inj[n] = base[(size_t)n * SS * SS];
  float cur = 0.f;
  #pragma unroll
  for (int n = 0; n < NC; n++) {
    base[(size_t)n * SS * SS] = cur;
    cur = fmaf(wC, cur, inj[n]);
  }
}

// ---- K7 v5: MFMA WKV, table-driven, 3 LDS planes (unchanged, verified R8) ----
__global__ __launch_bounds__(256) void k_wkv_mm(const float* __restrict__ rkvg,
                                                const float* __restrict__ states,
                                                const float* __restrict__ P1t,
                                                const float* __restrict__ P2t,
                                                const float* __restrict__ K1Ft,
                                                const float* __restrict__ EUt,
                                                float* __restrict__ Y) {
#if defined(__HIP_DEVICE_COMPILE__)
  __shared__ __align__(16) float    rsh[64 * COL];   // raw r; reused as P (packed)
  __shared__ __align__(16) unsigned k1sh[64 * COL];  // K1 = k*e^{-d i}; reused as state^T
  __shared__ __align__(16) unsigned vtsh[64 * COL];  // V^T[o][i], hi|lo
  unsigned* Pls = (unsigned*)rsh;

  int blk = blockIdx.x, tid = threadIdx.x;
  int n = blk & (NC - 1), h = (blk >> 5) & (HH - 1), b = blk >> 9;
  size_t rowbase = ((size_t)b * TT + n * CH) * DD + h * SS;
  const float* Rp = rkvg + rowbase;
  const float* Kp = rkvg + (size_t)1 * M_ROWS * DD + rowbase;
  const float* Vp = rkvg + (size_t)2 * M_ROWS * DD + rowbase;
  const float* stp = states + (size_t)blk * SS * SS;
  const float* P1h = P1t + (size_t)h * SS * SS;
  const float* P2h = P2t + (size_t)h * SS * SS;
  const float* K1h = K1Ft + (size_t)h * SS * SS;

  // ---- stage r,k,v planes; hoist state into registers (packed after P) ----
  int s_me = tid & 63, c0 = tid >> 6;
  float stv[16];
  #pragma unroll 4
  for (int j = 0; j < 16; j++) {
    int c = c0 + 4 * j;
    float rv = Rp[(size_t)c * DD + s_me];
    float kv = Kp[(size_t)c * DD + s_me];
    float vv = Vp[(size_t)c * DD + s_me];
    stv[j] = stp[(size_t)c * SS + s_me];         // state[s=c][o=s_me]
    rsh[c * COL + s_me] = rv;
    k1sh[c * COL + s_me] = packsplit(kv * K1h[(size_t)c * SS + s_me]);
    vtsh[s_me * COL + c] = packsplit(vv);
  }
  __syncthreads();

  int wid = tid >> 6, lane = tid & 63;
  int t_row = wid * 16 + (lane & 15);            // A-frag row
  int koff = (lane >> 4) * 8;                    // A/B-frag k offset within K=32

  // ---- A-frags via tables: R1 = r*P1[t_row][s], R2 = r*P2[t_row][s] ----
  short8 a1h[2], a1l[2], a2h[2], a2l[2];
  #pragma unroll
  for (int kh = 0; kh < 2; kh++) {
    int sb0 = kh * 32 + koff;
    size_t tb = (size_t)t_row * SS + sb0;
    float4 p1a = *(const float4*)&P1h[tb], p1b = *(const float4*)&P1h[tb + 4];
    float4 p2a = *(const float4*)&P2h[tb], p2b = *(const float4*)&P2h[tb + 4];
    float4 rva = *(const float4*)&rsh[t_row * COL + sb0];
    float4 rvb = *(const float4*)&rsh[t_row * COL + sb0 + 4];
    float p1[8] = {p1a.x, p1a.y, p1a.z, p1a.w, p1b.x, p1b.y, p1b.z, p1b.w};
    float p2[8] = {p2a.x, p2a.y, p2a.z, p2a.w, p2b.x, p2b.y, p2b.z, p2b.w};
    float rv[8] = {rva.x, rva.y, rva.z, rva.w, rvb.x, rvb.y, rvb.z, rvb.w};
    #pragma unroll
    for (int e = 0; e < 8; e++) {
      unsigned u1 = packsplit(rv[e] * p1[e]);
      unsigned u2 = packsplit(rv[e] * p2[e]);
      a1h[kh][e] = (short)(u1 >> 16); a1l[kh][e] = (short)(u1 & 0xffffu);
      a2h[kh][e] = (short)(u2 >> 16); a2l[kh][e] = (short)(u2 & 0xffffu);
    }
  }

  // ---- P = R1 * K1^T; mask i>=t; diagonal += beta via e^u-scaled pass ----
  #pragma unroll 1
  for (int it = 0; it < 4; it++) {
    int i_row = it * 16 + (lane & 15);
    f32x4 acc = {0.f, 0.f, 0.f, 0.f};
    f32x4 accu = {0.f, 0.f, 0.f, 0.f};
    bool anyKeep = (it >= wid);
    bool diag = (it == wid);
    if (anyKeep) {
      #pragma unroll
      for (int kh = 0; kh < 2; kh++) {
        const unsigned* q = &k1sh[i_row * COL + kh * 32 + koff];
        uint4 q0 = *(const uint4*)q;
        uint4 q1 = *(const uint4*)(q + 4);
        unsigned ar[8] = {q0.x, q0.y, q0.z, q0.w, q1.x, q1.y, q1.z, q1.w};
        short8 bh, bl;
        #pragma unroll
        for (int e = 0; e < 8; e++) {
          bh[e] = (short)(ar[e] >> 16);
          bl[e] = (short)(ar[e] & 0xffffu);
        }
        acc = __builtin_amdgcn_mfma_f32_16x16x32_bf16(a1h[kh], bh, acc, 0, 0, 0);
        acc = __builtin_amdgcn_mfma_f32_16x16x32_bf16(a1h[kh], bl, acc, 0, 0, 0);
        acc = __builtin_amdgcn_mfma_f32_16x16x32_bf16(a1l[kh], bh, acc, 0, 0, 0);
        if (diag) {
          int sb0 = kh * 32 + koff;
          float4 eua = *(const float4*)&EUt[h * SS + sb0];
          float4 eub = *(const float4*)&EUt[h * SS + sb0 + 4];
          float eu[8] = {eua.x, eua.y, eua.z, eua.w, eub.x, eub.y, eub.z, eub.w};
          short8 bhu, blu;
          #pragma unroll
          for (int e = 0; e < 8; e++) {
            float k1f = __uint_as_float(ar[e] & 0xffff0000u)
                      + __uint_as_float((ar[e] & 0xffffu) << 16);
            unsigned pu = packsplit(k1f * eu[e]);
            bhu[e] = (short)(pu >> 16); blu[e] = (short)(pu & 0xffffu);
          }
          accu = __builtin_amdgcn_mfma_f32_16x16x32_bf16(a1h[kh], bhu, accu, 0, 0, 0);
          accu = __builtin_amdgcn_mfma_f32_16x16x32_bf16(a1h[kh], blu, accu, 0, 0, 0);
          accu = __builtin_amdgcn_mfma_f32_16x16x32_bf16(a1l[kh], bhu, accu, 0, 0, 0);
        }
      }
    }
    #pragma unroll
    for (int rr = 0; rr < 4; rr++) {
      int trow = wid * 16 + (lane >> 4) * 4 + rr;
      int icol = it * 16 + (lane & 15);
      float p = acc[rr];
      p = (icol < trow) ? 0.f : p;
      if (icol == trow) p += accu[rr];
      Pls[trow * COL + icol] = packsplit(p);
    }
  }
  __syncthreads();   // all k1sh reads done -> safe to overwrite with state^T

  // ---- re-pack hoisted state into the dead k1sh plane: stsh[o][s] ----
  unsigned* stsh = k1sh;
  #pragma unroll
  for (int j = 0; j < 16; j++) {
    int c = c0 + 4 * j;
    stsh[s_me * COL + c] = packsplit(stv[j]);
  }
  __syncthreads();

  // ---- y = P*V + R2*state^T; store C-frags directly ----
  float* Yb = Y + ((size_t)b * TT + n * CH) * DD + h * SS;
  #pragma unroll 1
  for (int ot = 0; ot < 4; ot++) {
    int o_row = ot * 16 + (lane & 15);
    f32x4 acc = {0.f, 0.f, 0.f, 0.f};
    #pragma unroll
    for (int kh = 0; kh < 2; kh++) {
      short8 ph, pl, vh, vl, sh2, sl2;
      unpk8(&Pls[t_row * COL + kh * 32 + koff], ph, pl);
      unpk8(&vtsh[o_row * COL + kh * 32 + koff], vh, vl);
      acc = __builtin_amdgcn_mfma_f32_16x16x32_bf16(ph, vh, acc, 0, 0, 0);
      acc = __builtin_amdgcn_mfma_f32_16x16x32_bf16(ph, vl, acc, 0, 0, 0);
      acc = __builtin_amdgcn_mfma_f32_16x16x32_bf16(pl, vh, acc, 0, 0, 0);
      unpk8(&stsh[o_row * COL + kh * 32 + koff], sh2, sl2);
      acc = __builtin_amdgcn_mfma_f32_16x16x32_bf16(a2h[kh], sh2, acc, 0, 0, 0);
      acc = __builtin_amdgcn_mfma_f32_16x16x32_bf16(a2h[kh], sl2, acc, 0, 0, 0);
      acc = __builtin_amdgcn_mfma_f32_16x16x32_bf16(a2l[kh], sh2, acc, 0, 0, 0);
    }
    #pragma unroll
    for (int rr = 0; rr < 4; rr++) {
      int trow = wid * 16 + (lane >> 4) * 4 + rr;
      int oc = ot * 16 + (lane & 15);
      Yb[(size_t)trow * DD + oc] = acc[rr];
    }
  }
#endif  // __HIP_DEVICE_COMPILE__
}

// ---- K8 v3: GroupNorm + silu + LN + int8 act-quant ----
__global__ __launch_bounds__(256) void k_post(const float* __restrict__ Y,
                                              const float* __restrict__ G,
                                              const float* __restrict__ gn_g,
                                              const float* __restrict__ gn_b,
                                              const float* __restrict__ lg,
                                              const float* __restrict__ lb,
                                              char* __restrict__ xq4,
                                              float* __restrict__ ascale4) {
  __shared__ float slots[3 * 4];
  __shared__ float gmean[HH], grstd[HH];
  int m = blockIdx.x, tid = threadIdx.x;
  int d4 = tid * 4;
  float4 y4v = *(const float4*)&Y[(size_t)m * DD + d4];
  float4 g4v = *(const float4*)&G[(size_t)m * DD + d4];
  float y4[4] = {y4v.x, y4v.y, y4v.z, y4v.w};
  float g4[4] = {g4v.x, g4v.y, g4v.z, g4v.w};
  {
    float s = y4[0] + y4[1] + y4[2] + y4[3];
    s += __shfl_xor(s, 1); s += __shfl_xor(s, 2);
    s += __shfl_xor(s, 4); s += __shfl_xor(s, 8);
    float mn = s * (1.f / SS);
    float v2 = 0.f;
    #pragma unroll
    for (int q = 0; q < 4; q++) { float dv = y4[q] - mn; v2 += dv * dv; }
    v2 += __shfl_xor(v2, 1); v2 += __shfl_xor(v2, 2);
    v2 += __shfl_xor(v2, 4); v2 += __shfl_xor(v2, 8);
    if ((tid & 15) == 0) {
      gmean[tid >> 4] = mn;
      grstd[tid >> 4] = 1.f / sqrtf(v2 * (1.f / SS) + 1e-5f);
    }
  }
  __syncthreads();
  int hh = tid >> 4;
  float4 gg4 = *(const float4*)&gn_g[d4];
  float4 gb4 = *(const float4*)&gn_b[d4];
  float gg[4] = {gg4.x, gg4.y, gg4.z, gg4.w};
  float gb[4] = {gb4.x, gb4.y, gb4.z, gb4.w};
  float z[4];
  #pragma unroll
  for (int j = 0; j < 4; j++) {
    float yn = (y4[j] - gmean[hh]) * grstd[hh] * gg[j] + gb[j];
    float gv = g4[j];
    z[j] = yn * (gv / (1.f + expf(-gv)));
  }
  float mean = block_sum4(z[0] + z[1] + z[2] + z[3], &slots[0], tid) * (1.f / DD);
  float var = 0.f;
  #pragma unroll
  for (int j = 0; j < 4; j++) { float dv = z[j] - mean; var += dv * dv; }
  var = block_sum4(var, &slots[4], tid) * (1.f / DD);
  float rstd = 1.f / sqrtf(var + 1e-5f);
  float4 lg4 = *(const float4*)&lg[d4];
  float4 lb4 = *(const float4*)&lb[d4];
  float lgv[4] = {lg4.x, lg4.y, lg4.z, lg4.w};
  float lbv[4] = {lb4.x, lb4.y, lb4.z, lb4.w};
  float ln[4]; float aabs = 0.f;
  #pragma unroll
  for (int j = 0; j < 4; j++) {
    ln[j] = (z[j] - mean) * rstd * lgv[j] + lbv[j];
    aabs += fabsf(ln[j]);
  }
  float meanabs = block_sum4(aabs, &slots[8], tid) * (1.f / DD);
  float scale = fmaxf(meanabs, 1e-8f) * 2.5f * (1.f / 127.f);
  int q[4];
  #pragma unroll
  for (int j = 0; j < 4; j++)
    q[j] = (int)rintf(fminf(fmaxf(ln[j] / scale, -127.f), 127.f));
  *(int*)&xq4[(size_t)m * DD + d4] = pack4(q[0], q[1], q[2], q[3]);
  if (tid == 0) ascale4[m] = scale;
}

extern "C" void kernel_launch(void* const* d_in, const int* in_sizes, int n_in,
                              void* d_out, int out_size, void* d_ws, size_t ws_size,
                              hipStream_t stream) {
  const float* x         = (const float*)d_in[0];
  const float* mu_r      = (const float*)d_in[1];
  const float* mu_k      = (const float*)d_in[2];
  const float* mu_v      = (const float*)d_in[3];
  const float* mu_g      = (const float*)d_in[4];
  const float* log_decay = (const float*)d_in[5];
  const float* u         = (const float*)d_in[6];
  const float* proj_w    = (const float*)d_in[7];
  const float* ln_g      = (const float*)d_in[8];
  const float* ln_b      = (const float*)d_in[9];
  const float* gn_g      = (const float*)d_in[10];
  const float* gn_b      = (const float*)d_in[11];
  float* out = (float*)d_out;

  char* p = (char*)d_ws;
  float*  wscale = (float*)p;  p += 256;
  double* wpart  = (double*)p; p += 4096;
  char*   wq     = (char*)p;   p += (size_t)5 * DD * DD;
  float*  ascale = (float*)p;  p += (size_t)5 * M_ROWS * 4;
  char*   U      = p;          p += (size_t)40 * 1024 * 1024;
  char*   xq     = U;
  float*  Y      = (float*)U;
  char*   xq4    = U + (size_t)M_ROWS * DD * 4;
  float*  rkvg   = (float*)p;  p += (size_t)4 * M_ROWS * DD * 4;
  float*  states = (float*)p;  p += (size_t)BB * HH * NC * SS * SS * 4;
  float*  P1t    = (float*)p;  p += (size_t)HH * SS * SS * 4;   // 256 KB
  float*  P2t    = (float*)p;  p += (size_t)HH * SS * SS * 4;   // 256 KB
  float*  K1Ft   = (float*)p;  p += (size_t)HH * SS * SS * 4;   // 256 KB
  float*  K2Ft   = (float*)p;  p += (size_t)HH * SS * SS * 4;   // 256 KB
  float*  EUt    = (float*)p;  p += (size_t)HH * SS * 4;        // 4 KB

  hipLaunchKernelGGL(k_tab, dim3(HH * SS), dim3(64), 0, stream,
                     log_decay, u, P1t, P2t, K1Ft, K2Ft, EUt);
  hipLaunchKernelGGL(k_wscale_part, dim3(5, 64), dim3(256), 0, stream, proj_w, wpart);
  hipLaunchKernelGGL(k_wscale_fin, dim3(5), dim3(64), 0, stream, wpart, wscale);
  hipLaunchKernelGGL(k_wquant, dim3((5 * DD * DD) / 1024), dim3(256), 0, stream,
                     proj_w, wscale, wq);
  hipLaunchKernelGGL(k_prep_quant, dim3(M_ROWS), dim3(256), 0, stream,
                     x, mu_r, mu_k, mu_v, mu_g, ln_g, ln_b, xq, ascale);
  hipLaunchKernelGGL(k_gemm, dim3(M_ROWS / 256, DD / 256, 4), dim3(512), 0,
                     stream, xq, wq, ascale, wscale, 0, rkvg);
  hipLaunchKernelGGL(k_inj_mm, dim3(BB * HH * NC), dim3(256), 0, stream,
                     rkvg, K2Ft, states);
  hipLaunchKernelGGL(k_scan, dim3(BB * HH * 16), dim3(256), 0, stream,
                     log_decay, states);
  hipLaunchKernelGGL(k_wkv_mm, dim3(BB * HH * NC), dim3(256), 0, stream,
                     rkvg, states, P1t, P2t, K1Ft, EUt, Y);
  hipLaunchKernelGGL(k_post, dim3(M_ROWS), dim3(256), 0, stream,
                     Y, rkvg + (size_t)3 * M_ROWS * DD, gn_g, gn_b,
                     ln_g + 4 * DD, ln_b + 4 * DD,
                     xq4, ascale + 4 * M_ROWS);
  hipLaunchKernelGGL(k_gemm, dim3(M_ROWS / 256, DD / 256, 1), dim3(512), 0,
                     stream, xq4, wq,
                     ascale + 4 * M_ROWS, wscale, 4, out);
}

// Round 12
// 308.090 us; speedup vs baseline: 1.0834x; 1.0834x over previous
//
#include <hip/hip_runtime.h>
#include <hip/hip_bf16.h>

// Problem constants
#define BB 4
#define TT 2048
#define DD 1024
#define HH 16
#define SS 64
#define CH 64
#define NC (TT/CH)        // 32
#define M_ROWS (BB*TT)    // 8192
#define COL 68            // LDS row stride (words)

typedef __hip_bfloat16 bf16;
using int4v  = __attribute__((ext_vector_type(4))) int;
using short8 = __attribute__((ext_vector_type(8))) short;
using f32x4  = __attribute__((ext_vector_type(4))) float;

#if defined(__has_builtin)
#if __has_builtin(__builtin_amdgcn_global_load_lds)
#define HAVE_GLL 1
#endif
#if __has_builtin(__builtin_amdgcn_mfma_i32_16x16x64_i8)
#define HAVE_I8K64 1
#endif
#endif

#ifdef HAVE_GLL
static __device__ __forceinline__ void gload16(const void* g, void* l) {
  __builtin_amdgcn_global_load_lds(
      (const __attribute__((address_space(1))) void*)g,
      (__attribute__((address_space(3))) void*)l, 16, 0, 0);
}
#endif

// ---- wave-wide sum (64 lanes, deterministic butterfly) ----
static __device__ __forceinline__ float wave_sum(float v) {
  #pragma unroll
  for (int d = 1; d < 64; d <<= 1) v += __shfl_xor(v, d);
  return v;
}

// ---- block sum over 256 threads: shfl + 4-slot LDS, ONE barrier. ----
static __device__ __forceinline__ float block_sum4(float v, float* slot, int tid) {
  float w = wave_sum(v);
  if ((tid & 63) == 0) slot[tid >> 6] = w;
  __syncthreads();
  return slot[0] + slot[1] + slot[2] + slot[3];
}

static __device__ __forceinline__ int pack4(int a, int b, int c, int d) {
  return (a & 0xff) | ((b & 0xff) << 8) | ((c & 0xff) << 16) | ((d & 0xff) << 24);
}

// ---- split-bf16: pack f32 as (hi bf16 | lo bf16), reconstruction ~2^-16 rel ----
static __device__ __forceinline__ unsigned packsplit(float f) {
  unsigned b  = __float_as_uint(f);
  unsigned hb = b & 0xffff0000u;
  float fl = f - __uint_as_float(hb);
  unsigned lb = __float_as_uint(fl) >> 16;
  return hb | lb;
}

static __device__ __forceinline__ void unpk8(const unsigned* q, short8& h, short8& l) {
  uint4 q0 = *(const uint4*)q;
  uint4 q1 = *(const uint4*)(q + 4);
  unsigned ar[8] = {q0.x, q0.y, q0.z, q0.w, q1.x, q1.y, q1.z, q1.w};
  #pragma unroll
  for (int e = 0; e < 8; e++) {
    h[e] = (short)(ar[e] >> 16);
    l[e] = (short)(ar[e] & 0xffffu);
  }
}

// ---- K0: decay/exponential tables. ----
__global__ __launch_bounds__(64) void k_tab(const float* __restrict__ log_decay,
                                            const float* __restrict__ u,
                                            float* __restrict__ P1t,
                                            float* __restrict__ P2t,
                                            float* __restrict__ K1Ft,
                                            float* __restrict__ K2Ft,
                                            float* __restrict__ EUt) {
  int blk = blockIdx.x;              // h*64 + t
  int h = blk >> 6, t = blk & 63;
  int s = threadIdx.x;
  float d = expf(log_decay[h * SS + s]);
  size_t idx = (size_t)blk * SS + s;
  P1t[idx]  = expf(d * (float)t);
  P2t[idx]  = expf(-d * (float)(t + 1));
  K1Ft[idx] = expf(-d * (float)t);
  K2Ft[idx] = expf(-d * (float)(63 - t));
  if (t == 0) EUt[h * SS + s] = expf(u[h * SS + s]);
}

// ---- K1a: weight-scale partials. grid (5,64) ----
__global__ __launch_bounds__(256) void k_wscale_part(const float* __restrict__ w,
                                                     double* __restrict__ wpart) {
  __shared__ double red[256];
  int i = blockIdx.x, b = blockIdx.y, tid = threadIdx.x;
  const float* base = w + (size_t)i * DD * DD + (size_t)b * 16384;
  double s = 0.0;
  #pragma unroll
  for (int j = 0; j < 64; j++) s += (double)fabsf(base[tid + j * 256]);
  red[tid] = s; __syncthreads();
  for (int o = 128; o > 0; o >>= 1) {
    if (tid < o) red[tid] += red[tid + o];
    __syncthreads();
  }
  if (tid == 0) wpart[i * 64 + b] = red[0];
}

// ---- K1b: fold 64 partials per matrix in fixed order ----
__global__ __launch_bounds__(64) void k_wscale_fin(const double* __restrict__ wpart,
                                                   float* __restrict__ wscale) {
  int i = blockIdx.x;
  if (threadIdx.x == 0) {
    double s = 0.0;
    for (int b = 0; b < 64; b++) s += wpart[i * 64 + b];
    wscale[i] = fmaxf((float)(s * (1.0 / (DD * DD))), 1e-8f);
  }
}

// ---- K2 v2: ternary weight quant -> int8 {-1,0,1}, packed int stores ----
__global__ __launch_bounds__(256) void k_wquant(const float* __restrict__ w,
                                                const float* __restrict__ wscale,
                                                char* __restrict__ wq) {
  int idx4 = (blockIdx.x * 256 + threadIdx.x) * 4;
  int i = idx4 >> 20;
  float ws = wscale[i];
  float4 w4 = *(const float4*)&w[idx4];
  float vals[4] = {w4.x, w4.y, w4.z, w4.w};
  int q[4];
  #pragma unroll
  for (int j = 0; j < 4; j++) {
    float wn = fminf(fmaxf(vals[j] / ws, -1.f), 1.f);
    q[j] = (int)rintf(wn);
  }
  *(int*)&wq[idx4] = pack4(q[0], q[1], q[2], q[3]);
}

// ---- K3 v4: WAVE-PER-ROW token-shift + LN + act-quant (R11 fix).
// R11 counters: VALUBusy 66%, HBM 16% -> shfl/barrier-bound, not BW.
// Old: block-per-row, 12 butterflies x 4 waves = 288 shfl-instrs + 12
// barriers per row. New: lane owns 16 elems (float4 @ lane*4+256i,
// coalesced); each reduction = 16 in-lane adds + ONE 6-step butterfly:
// 72 shfl-instrs, ZERO barriers, zero LDS. 4 rows per 256-thr block. ----
__global__ __launch_bounds__(256) void k_prep_quant(
    const float* __restrict__ x, const float* __restrict__ mu_r,
    const float* __restrict__ mu_k, const float* __restrict__ mu_v,
    const float* __restrict__ mu_g, const float* __restrict__ ln_g,
    const float* __restrict__ ln_b, char* __restrict__ xq,
    float* __restrict__ ascale) {
  int tid = threadIdx.x;
  int wid = tid >> 6, lane = tid & 63;
  int m = blockIdx.x * 4 + wid;
  int t = m & (TT - 1);
  const float* xr = x + (size_t)m * DD;
  float xv[16], xs[16];
  #pragma unroll
  for (int i = 0; i < 4; i++) {
    int d0 = lane * 4 + 256 * i;
    float4 v = *(const float4*)&xr[d0];
    xv[4 * i + 0] = v.x; xv[4 * i + 1] = v.y;
    xv[4 * i + 2] = v.z; xv[4 * i + 3] = v.w;
    float4 s = (t > 0) ? *(const float4*)&xr[d0 - DD]
                       : (float4){0.f, 0.f, 0.f, 0.f};
    xs[4 * i + 0] = s.x; xs[4 * i + 1] = s.y;
    xs[4 * i + 2] = s.z; xs[4 * i + 3] = s.w;
  }
  const float* mus[4] = {mu_r, mu_k, mu_v, mu_g};
  #pragma unroll 1
  for (int p = 0; p < 4; p++) {
    float inp[16];
    float sum = 0.f;
    #pragma unroll
    for (int i = 0; i < 4; i++) {
      int d0 = lane * 4 + 256 * i;
      float4 mu4 = *(const float4*)&mus[p][d0];
      float mu[4] = {mu4.x, mu4.y, mu4.z, mu4.w};
      #pragma unroll
      for (int j = 0; j < 4; j++) {
        int e = 4 * i + j;
        inp[e] = xv[e] + (xs[e] - xv[e]) * mu[j];
        sum += inp[e];
      }
    }
    float mean = wave_sum(sum) * (1.f / DD);
    float var = 0.f;
    #pragma unroll
    for (int e = 0; e < 16; e++) { float dv = inp[e] - mean; var += dv * dv; }
    var = wave_sum(var) * (1.f / DD);
    float rstd = 1.f / sqrtf(var + 1e-5f);
    float ln[16]; float aabs = 0.f;
    #pragma unroll
    for (int i = 0; i < 4; i++) {
      int d0 = lane * 4 + 256 * i;
      float4 lg4 = *(const float4*)&ln_g[p * DD + d0];
      float4 lb4 = *(const float4*)&ln_b[p * DD + d0];
      float lg[4] = {lg4.x, lg4.y, lg4.z, lg4.w};
      float lb[4] = {lb4.x, lb4.y, lb4.z, lb4.w};
      #pragma unroll
      for (int j = 0; j < 4; j++) {
        int e = 4 * i + j;
        ln[e] = (inp[e] - mean) * rstd * lg[j] + lb[j];
        aabs += fabsf(ln[e]);
      }
    }
    float meanabs = wave_sum(aabs) * (1.f / DD);
    float scale = fmaxf(meanabs, 1e-8f) * 2.5f * (1.f / 127.f);
    char* xo = xq + ((size_t)p * M_ROWS + m) * DD;
    #pragma unroll
    for (int i = 0; i < 4; i++) {
      int q[4];
      #pragma unroll
      for (int j = 0; j < 4; j++)
        q[j] = (int)rintf(fminf(fmaxf(ln[4 * i + j] / scale, -127.f), 127.f));
      *(int*)&xo[lane * 4 + 256 * i] = pack4(q[0], q[1], q[2], q[3]);
    }
    if (lane == 0) ascale[p * M_ROWS + m] = scale;
  }
}

// ---- K4 v5 (z=4): INT8 MFMA GEMM, 256x256 tile, counted-vmcnt pipeline.
// (verified R11; bit-exact vs 128^2 version) ----
__global__ __launch_bounds__(512) void k_gemm(
    const char* __restrict__ Axq, const char* __restrict__ Wq,
    const float* __restrict__ ascale, const float* __restrict__ wscale,
    int projbase, float* __restrict__ outF) {
  __shared__ __align__(16) char As[3][256 * 64];
  __shared__ __align__(16) char Bs[3][256 * 64];
  int tid = threadIdx.x;
  int wvid = tid >> 6, lane = tid & 63;
  int wm = wvid >> 2, wn = wvid & 3;
  int m0 = blockIdx.x * 256, n0 = blockIdx.y * 256;
  int z = blockIdx.z;
  int proj = projbase + z;
  const char* Ap = Axq + ((size_t)z * M_ROWS + m0) * DD;
  const char* Wp = Wq + ((size_t)proj * DD + n0) * DD;
  int4v acc[8][4];
  #pragma unroll
  for (int i = 0; i < 8; i++)
    #pragma unroll
    for (int j = 0; j < 4; j++) acc[i][j] = (int4v){0, 0, 0, 0};

  int frow = lane & 15, fslot = lane >> 4;
  int srow_lo = tid >> 2;
  int sslot0  = tid & 3;

  auto stage_pass = [&](int k0, int q, char* Ad, char* Bd) {
    int rr = ((q & 1) << 7) + srow_lo;
    int sl = sslot0 ^ ((rr >> 1) & 3);
    if (q < 2) {
#ifdef HAVE_GLL
      gload16(&Ap[(size_t)rr * DD + k0 + sl * 16], &Ad[(q & 1) * 8192 + tid * 16]);
#else
      *(uint4*)&Ad[(q & 1) * 8192 + tid * 16] =
          *(const uint4*)&Ap[(size_t)rr * DD + k0 + sl * 16];
#endif
    } else {
#ifdef HAVE_GLL
      gload16(&Wp[(size_t)rr * DD + k0 + sl * 16], &Bd[(q & 1) * 8192 + tid * 16]);
#else
      *(uint4*)&Bd[(q & 1) * 8192 + tid * 16] =
          *(const uint4*)&Wp[(size_t)rr * DD + k0 + sl * 16];
#endif
    }
  };

  #pragma unroll
  for (int q = 0; q < 4; q++) stage_pass(0, q, As[0], Bs[0]);
  #pragma unroll
  for (int q = 0; q < 4; q++) stage_pass(64, q, As[1], Bs[1]);
#ifdef HAVE_GLL
  asm volatile("s_waitcnt vmcnt(4)" ::: "memory");
  __builtin_amdgcn_s_barrier();
#else
  __syncthreads();
#endif

  for (int kt = 0; kt < 16; ++kt) {
    const char* Abuf = As[kt % 3];
    const char* Bbuf = Bs[kt % 3];
    char* Anx = As[(kt + 2) % 3];
    char* Bnx = Bs[(kt + 2) % 3];
    int k0n = (kt + 2) * 64;
    bool do_stage = (kt + 2) < 16;
    int4v bfr[4];
    #pragma unroll
    for (int j = 0; j < 4; j++) {
      int r = 64 * wn + 16 * j + frow;
      bfr[j] = *(const int4v*)&Bbuf[r * 64 + (fslot ^ ((r >> 1) & 3)) * 16];
    }
    #pragma unroll
    for (int p = 0; p < 4; p++) {
      if (do_stage) stage_pass(k0n, p, Anx, Bnx);
      int4v af[2];
      #pragma unroll
      for (int e = 0; e < 2; e++) {
        int r = 128 * wm + 16 * (2 * p + e) + frow;
        af[e] = *(const int4v*)&Abuf[r * 64 + (fslot ^ ((r >> 1) & 3)) * 16];
      }
      __builtin_amdgcn_s_setprio(1);
#ifdef HAVE_I8K64
      #pragma unroll
      for (int e = 0; e < 2; e++)
        #pragma unroll
        for (int j = 0; j < 4; j++)
          acc[2 * p + e][j] =
              __builtin_amdgcn_mfma_i32_16x16x64_i8(af[e], bfr[j], acc[2 * p + e][j], 0, 0, 0);
#else
      #pragma unroll
      for (int e = 0; e < 2; e++)
        #pragma unroll
        for (int j = 0; j < 4; j++)
          #pragma unroll
          for (int hh2 = 0; hh2 < 2; hh2++) {
            long a8, b8;
            memcpy(&a8, ((const char*)&af[e]) + hh2 * 8, 8);
            memcpy(&b8, ((const char*)&bfr[j]) + hh2 * 8, 8);
            acc[2 * p + e][j] =
                __builtin_amdgcn_mfma_i32_16x16x32_i8(a8, b8, acc[2 * p + e][j], 0, 0, 0);
          }
#endif
      __builtin_amdgcn_s_setprio(0);
    }
    if (kt < 15) {
#ifdef HAVE_GLL
      if (kt + 2 < 16) asm volatile("s_waitcnt vmcnt(4)" ::: "memory");
      else             asm volatile("s_waitcnt vmcnt(0)" ::: "memory");
      __builtin_amdgcn_s_barrier();
#else
      __syncthreads();
#endif
    }
  }

  const float* asc = ascale + (size_t)z * M_ROWS + m0;
  float wsc = wscale[proj];
  int col = lane & 15, rg = lane >> 4;
  #pragma unroll
  for (int i = 0; i < 8; i++) {
    #pragma unroll
    for (int r = 0; r < 4; r++) {
      int mm = 128 * wm + 16 * i + rg * 4 + r;
      float s = asc[mm] * wsc;
      #pragma unroll
      for (int j = 0; j < 4; j++) {
        int nn = 64 * wn + 16 * j + col;
        outF[((size_t)z * M_ROWS + m0 + mm) * DD + (n0 + nn)] = (float)acc[i][j][r] * s;
      }
    }
  }
}

// ---- K4b (z=1): 128x128 double-buffered GEMM (verified R8/R10 version).
// Used for the final projection: grid (64,8,1)=512 blocks -> full GPU
// (the 256^2 kernel at z=1 gives only 128 blocks = half the CUs idle). ----
__global__ __launch_bounds__(256) void k_gemm128(
    const char* __restrict__ Axq, const char* __restrict__ Wq,
    const float* __restrict__ ascale, const float* __restrict__ wscale,
    int projbase, float* __restrict__ outF) {
  __shared__ __align__(16) char As[2][128 * 64];
  __shared__ __align__(16) char Bs[2][128 * 64];
  int tid = threadIdx.x;
  int wvid = tid >> 6, lane = tid & 63;
  int wm = wvid >> 1, wn = wvid & 1;
  int m0 = blockIdx.x * 128, n0 = blockIdx.y * 128;
  int z = blockIdx.z;
  int proj = projbase + z;
  const char* Ap = Axq + ((size_t)z * M_ROWS + m0) * DD;
  const char* Wp = Wq + ((size_t)proj * DD + n0) * DD;
  int4v acc[4][4];
  #pragma unroll
  for (int i = 0; i < 4; i++)
    #pragma unroll
    for (int j = 0; j < 4; j++) acc[i][j] = (int4v){0, 0, 0, 0};
  int row = tid >> 2, col16 = (tid & 3) * 16;
  int frow = lane & 15, fq16 = (lane >> 4) * 16;

  auto stage = [&](int k0, int buf) {
    #pragma unroll
    for (int q = 0; q < 2; q++) {
#ifdef HAVE_GLL
      gload16(&Ap[(size_t)(q * 64 + row) * DD + k0 + col16],
              &As[buf][q * 4096 + tid * 16]);
      gload16(&Wp[(size_t)(q * 64 + row) * DD + k0 + col16],
              &Bs[buf][q * 4096 + tid * 16]);
#else
      *(uint4*)&As[buf][(q * 64 + row) * 64 + col16] =
          *(const uint4*)&Ap[(size_t)(q * 64 + row) * DD + k0 + col16];
      *(uint4*)&Bs[buf][(q * 64 + row) * 64 + col16] =
          *(const uint4*)&Wp[(size_t)(q * 64 + row) * DD + k0 + col16];
#endif
    }
  };

  stage(0, 0);
  __syncthreads();
  int cur = 0;
  for (int k0 = 0; k0 < DD; k0 += 64) {
    if (k0 + 64 < DD) stage(k0 + 64, cur ^ 1);
#ifdef HAVE_I8K64
    int4v af[4], bfr[4];
    #pragma unroll
    for (int i = 0; i < 4; i++)
      af[i] = *(const int4v*)&As[cur][(64 * wm + 16 * i + frow) * 64 + fq16];
    #pragma unroll
    for (int j = 0; j < 4; j++)
      bfr[j] = *(const int4v*)&Bs[cur][(64 * wn + 16 * j + frow) * 64 + fq16];
    #pragma unroll
    for (int i = 0; i < 4; i++)
      #pragma unroll
      for (int j = 0; j < 4; j++)
        acc[i][j] = __builtin_amdgcn_mfma_i32_16x16x64_i8(af[i], bfr[j], acc[i][j], 0, 0, 0);
#else
    int fq8 = (lane >> 4) * 8;
    long afl[4][2], bfl[4][2];
    #pragma unroll
    for (int i = 0; i < 4; i++)
      #pragma unroll
      for (int h = 0; h < 2; h++)
        afl[i][h] = *(const long*)&As[cur][(64 * wm + 16 * i + frow) * 64 + h * 32 + fq8];
    #pragma unroll
    for (int j = 0; j < 4; j++)
      #pragma unroll
      for (int h = 0; h < 2; h++)
        bfl[j][h] = *(const long*)&Bs[cur][(64 * wn + 16 * j + frow) * 64 + h * 32 + fq8];
    #pragma unroll
    for (int i = 0; i < 4; i++)
      #pragma unroll
      for (int j = 0; j < 4; j++)
        #pragma unroll
        for (int h = 0; h < 2; h++)
          acc[i][j] = __builtin_amdgcn_mfma_i32_16x16x32_i8(afl[i][h], bfl[j][h], acc[i][j], 0, 0, 0);
#endif
    if (k0 + 64 < DD) {
      __syncthreads();
      cur ^= 1;
    }
  }
  const float* asc = ascale + (size_t)z * M_ROWS + m0;
  float wsc = wscale[proj];
  int col = lane & 15, rg = lane >> 4;
  #pragma unroll
  for (int i = 0; i < 4; i++) {
    #pragma unroll
    for (int r = 0; r < 4; r++) {
      int mm = 64 * wm + 16 * i + rg * 4 + r;
      float s = asc[mm] * wsc;
      #pragma unroll
      for (int j = 0; j < 4; j++) {
        int nn = 64 * wn + 16 * j + col;
        outF[((size_t)z * M_ROWS + m0 + mm) * DD + (n0 + nn)] = (float)acc[i][j][r] * s;
      }
    }
  }
}

// ---- K5 v2: MFMA injection (verified R10) ----
__global__ __launch_bounds__(256) void k_inj_mm(const float* __restrict__ rkvg,
                                                const float* __restrict__ K2Ft,
                                                float* __restrict__ states) {
#if defined(__HIP_DEVICE_COMPILE__)
  __shared__ __align__(16) unsigned k2t[64 * COL];
  __shared__ __align__(16) unsigned vtsh[64 * COL];
  int blk = blockIdx.x, tid = threadIdx.x;
  int n = blk & (NC - 1), h = (blk >> 5) & (HH - 1), b = blk >> 9;
  size_t rowbase = ((size_t)b * TT + n * CH) * DD + h * SS;
  const float* Kp = rkvg + (size_t)1 * M_ROWS * DD + rowbase;
  const float* Vp = rkvg + (size_t)2 * M_ROWS * DD + rowbase;
  const float* K2h = K2Ft + (size_t)h * SS * SS;

  int s_me = tid & 63, c0 = tid >> 6;
  #pragma unroll 4
  for (int j = 0; j < 16; j++) {
    int c = c0 + 4 * j;
    float kv = Kp[(size_t)c * DD + s_me];
    float vv = Vp[(size_t)c * DD + s_me];
    k2t[s_me * COL + c] = packsplit(kv * K2h[(size_t)c * SS + s_me]);
    vtsh[s_me * COL + c] = packsplit(vv);
  }
  __syncthreads();

  int wid = tid >> 6, lane = tid & 63;
  int s_row = wid * 16 + (lane & 15);
  int koff = (lane >> 4) * 8;
  short8 ah[2], al[2];
  #pragma unroll
  for (int kh = 0; kh < 2; kh++)
    unpk8(&k2t[s_row * COL + kh * 32 + koff], ah[kh], al[kh]);

  float* st = states + (size_t)blk * SS * SS;
  #pragma unroll 1
  for (int ot = 0; ot < 4; ot++) {
    int o_row = ot * 16 + (lane & 15);
    f32x4 acc = {0.f, 0.f, 0.f, 0.f};
    #pragma unroll
    for (int kh = 0; kh < 2; kh++) {
      short8 vh, vl;
      unpk8(&vtsh[o_row * COL + kh * 32 + koff], vh, vl);
      acc = __builtin_amdgcn_mfma_f32_16x16x32_bf16(ah[kh], vh, acc, 0, 0, 0);
      acc = __builtin_amdgcn_mfma_f32_16x16x32_bf16(ah[kh], vl, acc, 0, 0, 0);
      acc = __builtin_amdgcn_mfma_f32_16x16x32_bf16(al[kh], vh, acc, 0, 0, 0);
    }
    #pragma unroll
    for (int rr = 0; rr < 4; rr++) {
      int s = wid * 16 + (lane >> 4) * 4 + rr;
      int o = ot * 16 + (lane & 15);
      st[(size_t)s * SS + o] = acc[rr];
    }
  }
#endif
}

// ---- K6 v2: PARALLEL scan, loads hoisted ----
__global__ __launch_bounds__(256) void k_scan(const float* __restrict__ log_decay,
                                              float* __restrict__ states) {
  int blk = blockIdx.x;
  int bh = blk >> 4, sb = blk & 15;
  int h = bh & (HH - 1);
  int tid = threadIdx.x;
  int js = tid >> 6, o = tid & 63;
  int s = sb * 4 + js;
  float wC = expf(-64.f * expf(log_decay[h * SS + s]));
  float* base = states + (size_t)bh * NC * SS * SS + (size_t)s * SS + o;
  float inj[NC];
  #pragma unroll
  for (int n = 0; n < NC; n++) inj[n] = base[(size_t)n * SS * SS];
  float cur = 0.f;
  #pragma unroll
  for (int n = 0; n < NC; n++) {
    base[(size_t)n * SS * SS] = cur;
    cur = fmaf(wC, cur, inj[n]);
  }
}

// ---- K7 v5: MFMA WKV, table-driven, 3 LDS planes (verified R8) ----
__global__ __launch_bounds__(256) void k_wkv_mm(const float* __restrict__ rkvg,
                                                const float* __restrict__ states,
                                                const float* __restrict__ P1t,
                                                const float* __restrict__ P2t,
                                                const float* __restrict__ K1Ft,
                                                const float* __restrict__ EUt,
                                                float* __restrict__ Y) {
#if defined(__HIP_DEVICE_COMPILE__)
  __shared__ __align__(16) float    rsh[64 * COL];
  __shared__ __align__(16) unsigned k1sh[64 * COL];
  __shared__ __align__(16) unsigned vtsh[64 * COL];
  unsigned* Pls = (unsigned*)rsh;

  int blk = blockIdx.x, tid = threadIdx.x;
  int n = blk & (NC - 1), h = (blk >> 5) & (HH - 1), b = blk >> 9;
  size_t rowbase = ((size_t)b * TT + n * CH) * DD + h * SS;
  const float* Rp = rkvg + rowbase;
  const float* Kp = rkvg + (size_t)1 * M_ROWS * DD + rowbase;
  const float* Vp = rkvg + (size_t)2 * M_ROWS * DD + rowbase;
  const float* stp = states + (size_t)blk * SS * SS;
  const float* P1h = P1t + (size_t)h * SS * SS;
  const float* P2h = P2t + (size_t)h * SS * SS;
  const float* K1h = K1Ft + (size_t)h * SS * SS;

  int s_me = tid & 63, c0 = tid >> 6;
  float stv[16];
  #pragma unroll 4
  for (int j = 0; j < 16; j++) {
    int c = c0 + 4 * j;
    float rv = Rp[(size_t)c * DD + s_me];
    float kv = Kp[(size_t)c * DD + s_me];
    float vv = Vp[(size_t)c * DD + s_me];
    stv[j] = stp[(size_t)c * SS + s_me];
    rsh[c * COL + s_me] = rv;
    k1sh[c * COL + s_me] = packsplit(kv * K1h[(size_t)c * SS + s_me]);
    vtsh[s_me * COL + c] = packsplit(vv);
  }
  __syncthreads();

  int wid = tid >> 6, lane = tid & 63;
  int t_row = wid * 16 + (lane & 15);
  int koff = (lane >> 4) * 8;

  short8 a1h[2], a1l[2], a2h[2], a2l[2];
  #pragma unroll
  for (int kh = 0; kh < 2; kh++) {
    int sb0 = kh * 32 + koff;
    size_t tb = (size_t)t_row * SS + sb0;
    float4 p1a = *(const float4*)&P1h[tb], p1b = *(const float4*)&P1h[tb + 4];
    float4 p2a = *(const float4*)&P2h[tb], p2b = *(const float4*)&P2h[tb + 4];
    float4 rva = *(const float4*)&rsh[t_row * COL + sb0];
    float4 rvb = *(const float4*)&rsh[t_row * COL + sb0 + 4];
    float p1[8] = {p1a.x, p1a.y, p1a.z, p1a.w, p1b.x, p1b.y, p1b.z, p1b.w};
    float p2[8] = {p2a.x, p2a.y, p2a.z, p2a.w, p2b.x, p2b.y, p2b.z, p2b.w};
    float rv[8] = {rva.x, rva.y, rva.z, rva.w, rvb.x, rvb.y, rvb.z, rvb.w};
    #pragma unroll
    for (int e = 0; e < 8; e++) {
      unsigned u1 = packsplit(rv[e] * p1[e]);
      unsigned u2 = packsplit(rv[e] * p2[e]);
      a1h[kh][e] = (short)(u1 >> 16); a1l[kh][e] = (short)(u1 & 0xffffu);
      a2h[kh][e] = (short)(u2 >> 16); a2l[kh][e] = (short)(u2 & 0xffffu);
    }
  }

  #pragma unroll 1
  for (int it = 0; it < 4; it++) {
    int i_row = it * 16 + (lane & 15);
    f32x4 acc = {0.f, 0.f, 0.f, 0.f};
    f32x4 accu = {0.f, 0.f, 0.f, 0.f};
    bool anyKeep = (it >= wid);
    bool diag = (it == wid);
    if (anyKeep) {
      #pragma unroll
      for (int kh = 0; kh < 2; kh++) {
        const unsigned* q = &k1sh[i_row * COL + kh * 32 + koff];
        uint4 q0 = *(const uint4*)q;
        uint4 q1 = *(const uint4*)(q + 4);
        unsigned ar[8] = {q0.x, q0.y, q0.z, q0.w, q1.x, q1.y, q1.z, q1.w};
        short8 bh, bl;
        #pragma unroll
        for (int e = 0; e < 8; e++) {
          bh[e] = (short)(ar[e] >> 16);
          bl[e] = (short)(ar[e] & 0xffffu);
        }
        acc = __builtin_amdgcn_mfma_f32_16x16x32_bf16(a1h[kh], bh, acc, 0, 0, 0);
        acc = __builtin_amdgcn_mfma_f32_16x16x32_bf16(a1h[kh], bl, acc, 0, 0, 0);
        acc = __builtin_amdgcn_mfma_f32_16x16x32_bf16(a1l[kh], bh, acc, 0, 0, 0);
        if (diag) {
          int sb0 = kh * 32 + koff;
          float4 eua = *(const float4*)&EUt[h * SS + sb0];
          float4 eub = *(const float4*)&EUt[h * SS + sb0 + 4];
          float eu[8] = {eua.x, eua.y, eua.z, eua.w, eub.x, eub.y, eub.z, eub.w};
          short8 bhu, blu;
          #pragma unroll
          for (int e = 0; e < 8; e++) {
            float k1f = __uint_as_float(ar[e] & 0xffff0000u)
                      + __uint_as_float((ar[e] & 0xffffu) << 16);
            unsigned pu = packsplit(k1f * eu[e]);
            bhu[e] = (short)(pu >> 16); blu[e] = (short)(pu & 0xffffu);
          }
          accu = __builtin_amdgcn_mfma_f32_16x16x32_bf16(a1h[kh], bhu, accu, 0, 0, 0);
          accu = __builtin_amdgcn_mfma_f32_16x16x32_bf16(a1h[kh], blu, accu, 0, 0, 0);
          accu = __builtin_amdgcn_mfma_f32_16x16x32_bf16(a1l[kh], bhu, accu, 0, 0, 0);
        }
      }
    }
    #pragma unroll
    for (int rr = 0; rr < 4; rr++) {
      int trow = wid * 16 + (lane >> 4) * 4 + rr;
      int icol = it * 16 + (lane & 15);
      float p = acc[rr];
      p = (icol < trow) ? 0.f : p;
      if (icol == trow) p += accu[rr];
      Pls[trow * COL + icol] = packsplit(p);
    }
  }
  __syncthreads();

  unsigned* stsh = k1sh;
  #pragma unroll
  for (int j = 0; j < 16; j++) {
    int c = c0 + 4 * j;
    stsh[s_me * COL + c] = packsplit(stv[j]);
  }
  __syncthreads();

  float* Yb = Y + ((size_t)b * TT + n * CH) * DD + h * SS;
  #pragma unroll 1
  for (int ot = 0; ot < 4; ot++) {
    int o_row = ot * 16 + (lane & 15);
    f32x4 acc = {0.f, 0.f, 0.f, 0.f};
    #pragma unroll
    for (int kh = 0; kh < 2; kh++) {
      short8 ph, pl, vh, vl, sh2, sl2;
      unpk8(&Pls[t_row * COL + kh * 32 + koff], ph, pl);
      unpk8(&vtsh[o_row * COL + kh * 32 + koff], vh, vl);
      acc = __builtin_amdgcn_mfma_f32_16x16x32_bf16(ph, vh, acc, 0, 0, 0);
      acc = __builtin_amdgcn_mfma_f32_16x16x32_bf16(ph, vl, acc, 0, 0, 0);
      acc = __builtin_amdgcn_mfma_f32_16x16x32_bf16(pl, vh, acc, 0, 0, 0);
      unpk8(&stsh[o_row * COL + kh * 32 + koff], sh2, sl2);
      acc = __builtin_amdgcn_mfma_f32_16x16x32_bf16(a2h[kh], sh2, acc, 0, 0, 0);
      acc = __builtin_amdgcn_mfma_f32_16x16x32_bf16(a2h[kh], sl2, acc, 0, 0, 0);
      acc = __builtin_amdgcn_mfma_f32_16x16x32_bf16(a2l[kh], sh2, acc, 0, 0, 0);
    }
    #pragma unroll
    for (int rr = 0; rr < 4; rr++) {
      int trow = wid * 16 + (lane >> 4) * 4 + rr;
      int oc = ot * 16 + (lane & 15);
      Yb[(size_t)trow * DD + oc] = acc[rr];
    }
  }
#endif
}

// ---- K8 v3: GroupNorm + silu + LN + int8 act-quant ----
__global__ __launch_bounds__(256) void k_post(const float* __restrict__ Y,
                                              const float* __restrict__ G,
                                              const float* __restrict__ gn_g,
                                              const float* __restrict__ gn_b,
                                              const float* __restrict__ lg,
                                              const float* __restrict__ lb,
                                              char* __restrict__ xq4,
                                              float* __restrict__ ascale4) {
  __shared__ float slots[3 * 4];
  __shared__ float gmean[HH], grstd[HH];
  int m = blockIdx.x, tid = threadIdx.x;
  int d4 = tid * 4;
  float4 y4v = *(const float4*)&Y[(size_t)m * DD + d4];
  float4 g4v = *(const float4*)&G[(size_t)m * DD + d4];
  float y4[4] = {y4v.x, y4v.y, y4v.z, y4v.w};
  float g4[4] = {g4v.x, g4v.y, g4v.z, g4v.w};
  {
    float s = y4[0] + y4[1] + y4[2] + y4[3];
    s += __shfl_xor(s, 1); s += __shfl_xor(s, 2);
    s += __shfl_xor(s, 4); s += __shfl_xor(s, 8);
    float mn = s * (1.f / SS);
    float v2 = 0.f;
    #pragma unroll
    for (int q = 0; q < 4; q++) { float dv = y4[q] - mn; v2 += dv * dv; }
    v2 += __shfl_xor(v2, 1); v2 += __shfl_xor(v2, 2);
    v2 += __shfl_xor(v2, 4); v2 += __shfl_xor(v2, 8);
    if ((tid & 15) == 0) {
      gmean[tid >> 4] = mn;
      grstd[tid >> 4] = 1.f / sqrtf(v2 * (1.f / SS) + 1e-5f);
    }
  }
  __syncthreads();
  int hh = tid >> 4;
  float4 gg4 = *(const float4*)&gn_g[d4];
  float4 gb4 = *(const float4*)&gn_b[d4];
  float gg[4] = {gg4.x, gg4.y, gg4.z, gg4.w};
  float gb[4] = {gb4.x, gb4.y, gb4.z, gb4.w};
  float z[4];
  #pragma unroll
  for (int j = 0; j < 4; j++) {
    float yn = (y4[j] - gmean[hh]) * grstd[hh] * gg[j] + gb[j];
    float gv = g4[j];
    z[j] = yn * (gv / (1.f + expf(-gv)));
  }
  float mean = block_sum4(z[0] + z[1] + z[2] + z[3], &slots[0], tid) * (1.f / DD);
  float var = 0.f;
  #pragma unroll
  for (int j = 0; j < 4; j++) { float dv = z[j] - mean; var += dv * dv; }
  var = block_sum4(var, &slots[4], tid) * (1.f / DD);
  float rstd = 1.f / sqrtf(var + 1e-5f);
  float4 lg4 = *(const float4*)&lg[d4];
  float4 lb4 = *(const float4*)&lb[d4];
  float lgv[4] = {lg4.x, lg4.y, lg4.z, lg4.w};
  float lbv[4] = {lb4.x, lb4.y, lb4.z, lb4.w};
  float ln[4]; float aabs = 0.f;
  #pragma unroll
  for (int j = 0; j < 4; j++) {
    ln[j] = (z[j] - mean) * rstd * lgv[j] + lbv[j];
    aabs += fabsf(ln[j]);
  }
  float meanabs = block_sum4(aabs, &slots[8], tid) * (1.f / DD);
  float scale = fmaxf(meanabs, 1e-8f) * 2.5f * (1.f / 127.f);
  int q[4];
  #pragma unroll
  for (int j = 0; j < 4; j++)
    q[j] = (int)rintf(fminf(fmaxf(ln[j] / scale, -127.f), 127.f));
  *(int*)&xq4[(size_t)m * DD + d4] = pack4(q[0], q[1], q[2], q[3]);
  if (tid == 0) ascale4[m] = scale;
}

extern "C" void kernel_launch(void* const* d_in, const int* in_sizes, int n_in,
                              void* d_out, int out_size, void* d_ws, size_t ws_size,
                              hipStream_t stream) {
  const float* x         = (const float*)d_in[0];
  const float* mu_r      = (const float*)d_in[1];
  const float* mu_k      = (const float*)d_in[2];
  const float* mu_v      = (const float*)d_in[3];
  const float* mu_g      = (const float*)d_in[4];
  const float* log_decay = (const float*)d_in[5];
  const float* u         = (const float*)d_in[6];
  const float* proj_w    = (const float*)d_in[7];
  const float* ln_g      = (const float*)d_in[8];
  const float* ln_b      = (const float*)d_in[9];
  const float* gn_g      = (const float*)d_in[10];
  const float* gn_b      = (const float*)d_in[11];
  float* out = (float*)d_out;

  char* p = (char*)d_ws;
  float*  wscale = (float*)p;  p += 256;
  double* wpart  = (double*)p; p += 4096;
  char*   wq     = (char*)p;   p += (size_t)5 * DD * DD;
  float*  ascale = (float*)p;  p += (size_t)5 * M_ROWS * 4;
  char*   U      = p;          p += (size_t)40 * 1024 * 1024;
  char*   xq     = U;
  float*  Y      = (float*)U;
  char*   xq4    = U + (size_t)M_ROWS * DD * 4;
  float*  rkvg   = (float*)p;  p += (size_t)4 * M_ROWS * DD * 4;
  float*  states = (float*)p;  p += (size_t)BB * HH * NC * SS * SS * 4;
  float*  P1t    = (float*)p;  p += (size_t)HH * SS * SS * 4;
  float*  P2t    = (float*)p;  p += (size_t)HH * SS * SS * 4;
  float*  K1Ft   = (float*)p;  p += (size_t)HH * SS * SS * 4;
  float*  K2Ft   = (float*)p;  p += (size_t)HH * SS * SS * 4;
  float*  EUt    = (float*)p;  p += (size_t)HH * SS * 4;

  hipLaunchKernelGGL(k_tab, dim3(HH * SS), dim3(64), 0, stream,
                     log_decay, u, P1t, P2t, K1Ft, K2Ft, EUt);
  hipLaunchKernelGGL(k_wscale_part, dim3(5, 64), dim3(256), 0, stream, proj_w, wpart);
  hipLaunchKernelGGL(k_wscale_fin, dim3(5), dim3(64), 0, stream, wpart, wscale);
  hipLaunchKernelGGL(k_wquant, dim3((5 * DD * DD) / 1024), dim3(256), 0, stream,
                     proj_w, wscale, wq);
  hipLaunchKernelGGL(k_prep_quant, dim3(M_ROWS / 4), dim3(256), 0, stream,
                     x, mu_r, mu_k, mu_v, mu_g, ln_g, ln_b, xq, ascale);
  hipLaunchKernelGGL(k_gemm, dim3(M_ROWS / 256, DD / 256, 4), dim3(512), 0,
                     stream, xq, wq, ascale, wscale, 0, rkvg);
  hipLaunchKernelGGL(k_inj_mm, dim3(BB * HH * NC), dim3(256), 0, stream,
                     rkvg, K2Ft, states);
  hipLaunchKernelGGL(k_scan, dim3(BB * HH * 16), dim3(256), 0, stream,
                     log_decay, states);
  hipLaunchKernelGGL(k_wkv_mm, dim3(BB * HH * NC), dim3(256), 0, stream,
                     rkvg, states, P1t, P2t, K1Ft, EUt, Y);
  hipLaunchKernelGGL(k_post, dim3(M_ROWS), dim3(256), 0, stream,
                     Y, rkvg + (size_t)3 * M_ROWS * DD, gn_g, gn_b,
                     ln_g + 4 * DD, ln_b + 4 * DD,
                     xq4, ascale + 4 * M_ROWS);
  hipLaunchKernelGGL(k_gemm128, dim3(M_ROWS / 128, DD / 128, 1), dim3(256), 0,
                     stream, xq4, wq,
                     ascale + 4 * M_ROWS, wscale, 4, out);
}